// Round 11
// baseline (2152.598 us; speedup 1.0000x reference)
//
#include <hip/hip_runtime.h>
#include <math.h>

// Problem constants: B=4, H=384, W=1280, NUM=8, IDX_REF=4
static constexpr int B_ = 4;
static constexpr int H_ = 384;
static constexpr int W_ = 1280;
static constexpr int HW_ = H_ * W_;

typedef float v2f __attribute__((ext_vector_type(2)));

// ---------------------------------------------------------------------------
// Guidance band = [normal(3), left(3), right(3), warp(right)-left(3)]
// layout (g, 12, rows, W) covering global rows [y0g, y0g+rows)
// ---------------------------------------------------------------------------
__global__ __launch_bounds__(256) void guidance_band(
    const float* __restrict__ disp, const float* __restrict__ normal,
    const float* __restrict__ left, const float* __restrict__ right,
    float* __restrict__ guid, int b0, int g, int y0g, int rows)
{
  int idx = blockIdx.x * 256 + threadIdx.x;
  if (idx >= g * rows * W_) return;
  int x = idx % W_;
  int t = idx / W_;
  int yr = t % rows;
  int gi = t / rows;
  int y = y0g + yr;
  int b = b0 + gi;
  int p = y * W_ + x;

  float d = disp[(size_t)b * HW_ + p];
  float xs = (float)x - d;
  float x0f = floorf(xs);
  int x0 = (int)x0f;
  float w1 = xs - x0f;
  int xi0 = x0, xi1 = x0 + 1;
  float v0 = (xi0 >= 0 && xi0 < W_) ? 1.f : 0.f;
  float v1 = (xi1 >= 0 && xi1 < W_) ? 1.f : 0.f;
  int xc0 = min(max(xi0, 0), W_ - 1);
  int xc1 = min(max(xi1, 0), W_ - 1);
  float w0f = (1.f - w1) * v0;
  float w1f = w1 * v1;

#pragma unroll
  for (int c = 0; c < 3; c++) {
    const float* rrow = right + (size_t)(b * 3 + c) * HW_ + (size_t)y * W_;
    float l = left[(size_t)(b * 3 + c) * HW_ + p];
    float n = normal[(size_t)(b * 3 + c) * HW_ + p];
    float r = rrow[x];
    float warped = w0f * rrow[xc0] + w1f * rrow[xc1];
    size_t base = ((size_t)gi * 12) * rows * W_ + (size_t)yr * W_ + x;
    size_t cs = (size_t)rows * W_;
    guid[base + (size_t)c * cs]       = n;
    guid[base + (size_t)(3 + c) * cs] = l;
    guid[base + (size_t)(6 + c) * cs] = r;
    guid[base + (size_t)(9 + c) * cs] = warped - l;
  }
}

// ---------------------------------------------------------------------------
// Banded 3x3 conv, 2x2 pixels/thread, 32x32 tile / 256 threads, 8 output
// channels per block. R11 change vs R10: horizontally-adjacent accumulator
// pairs are computed as float2 vector FMAs (__builtin_elementwise_fma on
// ext_vector_type(2) -> v_pk_fma_f32, 2 fp32 FMA per instruction) with a
// broadcast scalar weight -> halves FMA instruction count (R10 diagnosis:
// conv2 is VALU-issue-bound, 198 us issue vs 116 us scalar-FMA floor).
// Per accumulator lane the operand sequence (tap order w0..w8, ci
// ascending) is unchanged -> bit-identical numerics.
// CHUNK=4: LDS 19.6 KB -> 8 blocks/CU. coi fastest in grid for L3 reuse.
// ---------------------------------------------------------------------------
#define CONV_CO4(CO, AT, AB)                                                   \
  {                                                                            \
    const float* wp = wgt + ((size_t)(co0 + (CO)) * C_IN + ci) * 9;            \
    float w0 = wp[0], w1 = wp[1], w2 = wp[2], w3 = wp[3], w4 = wp[4];          \
    float w5 = wp[5], w6 = wp[6], w7 = wp[7], w8 = wp[8];                      \
    AT = __builtin_elementwise_fma(P0, (v2f){w0, w0}, AT);                     \
    AT = __builtin_elementwise_fma(P1, (v2f){w1, w1}, AT);                     \
    AT = __builtin_elementwise_fma(P2, (v2f){w2, w2}, AT);                     \
    AT = __builtin_elementwise_fma(Q0, (v2f){w3, w3}, AT);                     \
    AT = __builtin_elementwise_fma(Q1, (v2f){w4, w4}, AT);                     \
    AT = __builtin_elementwise_fma(Q2, (v2f){w5, w5}, AT);                     \
    AT = __builtin_elementwise_fma(R0, (v2f){w6, w6}, AT);                     \
    AT = __builtin_elementwise_fma(R1, (v2f){w7, w7}, AT);                     \
    AT = __builtin_elementwise_fma(R2, (v2f){w8, w8}, AT);                     \
    AB = __builtin_elementwise_fma(Q0, (v2f){w0, w0}, AB);                     \
    AB = __builtin_elementwise_fma(Q1, (v2f){w1, w1}, AB);                     \
    AB = __builtin_elementwise_fma(Q2, (v2f){w2, w2}, AB);                     \
    AB = __builtin_elementwise_fma(R0, (v2f){w3, w3}, AB);                     \
    AB = __builtin_elementwise_fma(R1, (v2f){w4, w4}, AB);                     \
    AB = __builtin_elementwise_fma(R2, (v2f){w5, w5}, AB);                     \
    AB = __builtin_elementwise_fma(S0, (v2f){w6, w6}, AB);                     \
    AB = __builtin_elementwise_fma(S1, (v2f){w7, w7}, AB);                     \
    AB = __builtin_elementwise_fma(S2, (v2f){w8, w8}, AB);                     \
  }

template <int C_IN, int C_OUT, int CHUNK, bool BNRELU>
__global__ __launch_bounds__(256, 8) void conv3x3_px4(
    const float* __restrict__ in, const float* __restrict__ wgt,
    const float* __restrict__ bn_g, const float* __restrict__ bn_b,
    const float* __restrict__ bn_m, const float* __restrict__ bn_v,
    float* __restrict__ out,
    int in_y0, int in_rows, int out_y0, int out_rows)
{
  constexpr int TX = 32, TY = 32;
  static_assert(C_IN % CHUNK == 0, "chunking");
  static_assert(C_OUT % 8 == 0, "co tiling");
  constexpr int NCO = C_OUT / 8;
  constexpr int LH = TY + 2;      // 34
  constexpr int LWS = 36;         // 34 used + 2 pad; 16B-aligned rows
  constexpr int QPC = LH * 9;     // 306 quads per channel tile

  __shared__ float smem[CHUNK][LH][LWS];

  const int tilesX = W_ / TX;     // 40
  const int tilesY = (out_rows + TY - 1) / TY;
  int t = blockIdx.x;
  int coi = t % NCO;  t /= NCO;    // coi FASTEST: co-siblings share L3 tile
  int txi = t % tilesX; t /= tilesX;
  int tyi = t % tilesY;
  int gi  = t / tilesY;
  const int x0  = txi * TX;
  const int oy0 = out_y0 + tyi * TY;
  const int co0 = coi * 8;

  const int tid = threadIdx.x;
  const int lx2 = (tid & 15) * 2;   // cols lx2, lx2+1
  const int ly2 = (tid >> 4) * 2;   // rows ly2, ly2+1

  v2f aT0 = {0.f, 0.f}, aT1 = {0.f, 0.f}, aT2 = {0.f, 0.f}, aT3 = {0.f, 0.f};
  v2f aT4 = {0.f, 0.f}, aT5 = {0.f, 0.f}, aT6 = {0.f, 0.f}, aT7 = {0.f, 0.f};
  v2f aB0 = {0.f, 0.f}, aB1 = {0.f, 0.f}, aB2 = {0.f, 0.f}, aB3 = {0.f, 0.f};
  v2f aB4 = {0.f, 0.f}, aB5 = {0.f, 0.f}, aB6 = {0.f, 0.f}, aB7 = {0.f, 0.f};

  for (int c0 = 0; c0 < C_IN; c0 += CHUNK) {
    // ---- quad-vectorized staging ----
    for (int i = tid; i < CHUNK * QPC; i += 256) {
      int c  = i / QPC;
      int r  = i - c * QPC;
      int yy = r / 9;
      int q  = r - yy * 9;
      int gy = oy0 + yy - 1;
      int by = gy - in_y0;
      int gx = x0 + 4 * q - 1;
      float v0 = 0.f, v1 = 0.f, v2 = 0.f, v3 = 0.f;
      if ((unsigned)by < (unsigned)in_rows) {
        const float* src = in + ((size_t)(gi * C_IN + c0 + c) * in_rows + by) * W_;
        v0 = ((unsigned)(gx + 0) < (unsigned)W_) ? src[gx + 0] : 0.f;
        v1 = ((unsigned)(gx + 1) < (unsigned)W_) ? src[gx + 1] : 0.f;
        v2 = ((unsigned)(gx + 2) < (unsigned)W_) ? src[gx + 2] : 0.f;
        v3 = ((unsigned)(gx + 3) < (unsigned)W_) ? src[gx + 3] : 0.f;
      }
      float* dst = &smem[c][yy][4 * q];
      dst[0] = v0; dst[1] = v1; dst[2] = v2; dst[3] = v3;
    }
    __syncthreads();

    for (int c = 0; c < CHUNK; c++) {
      const float* r0p = &smem[c][ly2 + 0][lx2];
      const float* r1p = &smem[c][ly2 + 1][lx2];
      const float* r2p = &smem[c][ly2 + 2][lx2];
      const float* r3p = &smem[c][ly2 + 3][lx2];
      v2f q00 = *(const v2f*)(r0p), q01 = *(const v2f*)(r0p + 2);
      v2f q10 = *(const v2f*)(r1p), q11 = *(const v2f*)(r1p + 2);
      v2f q20 = *(const v2f*)(r2p), q21 = *(const v2f*)(r2p + 2);
      v2f q30 = *(const v2f*)(r3p), q31 = *(const v2f*)(r3p + 2);
      // pairs: P=row0, Q=row1, R=row2, S=row3; X0={i0,i1} X1={i1,i2} X2={i2,i3}
      v2f P0 = q00, P2 = q01, P1 = {q00.y, q01.x};
      v2f Q0 = q10, Q2 = q11, Q1 = {q10.y, q11.x};
      v2f R0 = q20, R2 = q21, R1 = {q20.y, q21.x};
      v2f S0 = q30, S2 = q31, S1 = {q30.y, q31.x};
      const int ci = c0 + c;
      CONV_CO4(0, aT0, aB0)
      CONV_CO4(1, aT1, aB1)
      CONV_CO4(2, aT2, aB2)
      CONV_CO4(3, aT3, aB3)
      CONV_CO4(4, aT4, aB4)
      CONV_CO4(5, aT5, aB5)
      CONV_CO4(6, aT6, aB6)
      CONV_CO4(7, aT7, aB7)
    }
    __syncthreads();
  }

  const int oyA = oy0 + ly2;
  const int oyB = oyA + 1;
  const int ox  = x0 + lx2;
  const bool okA = (oyA < out_y0 + out_rows);
  const bool okB = (oyB < out_y0 + out_rows);

  v2f accT[8] = {aT0, aT1, aT2, aT3, aT4, aT5, aT6, aT7};
  v2f accB[8] = {aB0, aB1, aB2, aB3, aB4, aB5, aB6, aB7};
#pragma unroll
  for (int j = 0; j < 8; j++) {
    float r00 = accT[j].x, r01 = accT[j].y;
    float r10 = accB[j].x, r11 = accB[j].y;
    const int co = co0 + j;
    if constexpr (BNRELU) {
      float s = bn_g[co] * rsqrtf(bn_v[co] + 1e-5f);
      float o = bn_b[co] - bn_m[co] * s;
      r00 = fmaxf(r00 * s + o, 0.f);
      r01 = fmaxf(r01 * s + o, 0.f);
      r10 = fmaxf(r10 * s + o, 0.f);
      r11 = fmaxf(r11 * s + o, 0.f);
    }
    float* base = out + ((size_t)(gi * C_OUT + co) * out_rows) * W_;
    if (okA) { float2 v = {r00, r01}; *(float2*)&base[(size_t)(oyA - out_y0) * W_ + ox] = v; }
    if (okB) { float2 v = {r10, r11}; *(float2*)&base[(size_t)(oyB - out_y0) * W_ + ox] = v; }
  }
}

// ---------------------------------------------------------------------------
// Fused propagation epilogue over a band.
// oa layout (g, 24, rows, W): [o1(8)=dy, o2(8)=dx, aff_raw(8)]
// ---------------------------------------------------------------------------
__device__ __forceinline__ float bilin1(const float* __restrict__ img,
                                        float ys, float xs)
{
  float y0f = floorf(ys), x0f = floorf(xs);
  int y0 = (int)y0f, x0 = (int)x0f;
  float wy1 = ys - y0f, wx1 = xs - x0f;
  float wy0 = 1.f - wy1, wx0 = 1.f - wx1;
  int y1 = y0 + 1, x1 = x0 + 1;
  float vy0 = (y0 >= 0 && y0 < H_) ? 1.f : 0.f;
  float vy1 = (y1 >= 0 && y1 < H_) ? 1.f : 0.f;
  float vx0 = (x0 >= 0 && x0 < W_) ? 1.f : 0.f;
  float vx1 = (x1 >= 0 && x1 < W_) ? 1.f : 0.f;
  int yc0 = min(max(y0, 0), H_ - 1), yc1 = min(max(y1, 0), H_ - 1);
  int xc0 = min(max(x0, 0), W_ - 1), xc1 = min(max(x1, 0), W_ - 1);
  const float* r0 = img + (size_t)yc0 * W_;
  const float* r1 = img + (size_t)yc1 * W_;
  float v00 = r0[xc0], v01 = r0[xc1], v10 = r1[xc0], v11 = r1[xc1];
  return (wy0 * vy0) * ((wx0 * vx0) * v00 + (wx1 * vx1) * v01) +
         (wy1 * vy1) * ((wx0 * vx0) * v10 + (wx1 * vx1) * v11);
}

__global__ __launch_bounds__(256) void final_band(
    const float* __restrict__ oa, const float* __restrict__ conf,
    const float* __restrict__ disp, const float* __restrict__ asc,
    float* __restrict__ out, int b0, int g, int y0g, int rows)
{
  int idx = blockIdx.x * 256 + threadIdx.x;
  if (idx >= g * rows * W_) return;
  int x = idx % W_;
  int t = idx / W_;
  int yr = t % rows;
  int gi = t / rows;
  int y = y0g + yr;
  int b = b0 + gi;
  int p = y * W_ + x;

  const float scale = 1.f / (asc[0] + 1e-8f);
  const float* cimg = conf + (size_t)b * HW_;
  const float* dimg = disp + (size_t)b * HW_;
  const float* oab = oa + (size_t)gi * 24 * rows * W_;
  const size_t cs = (size_t)rows * W_;
  const size_t q = (size_t)yr * W_ + x;

  float offy[8], offx[8], a[8];
#pragma unroll
  for (int k = 0; k < 8; k++) {
    offy[k] = oab[(size_t)k * cs + q];
    offx[k] = oab[(size_t)(8 + k) * cs + q];
    float ar = oab[(size_t)(16 + k) * cs + q];
    float ca = bilin1(cimg, (float)y + offy[k], (float)x + offx[k]);
    a[k] = tanhf(ar) * scale * ca;
  }

  float s = 1e-4f;
#pragma unroll
  for (int k = 0; k < 8; k++) s += fabsf(a[k]);
  s = fmaxf(s, 1.f);
  float inv = 1.f / s;
  float suma = 0.f;
#pragma unroll
  for (int k = 0; k < 8; k++) { a[k] *= inv; suma += a[k]; }
  float aref = 1.f - suma;

  float inter = 0.f;
#pragma unroll
  for (int k9 = 0; k9 < 9; k9++) {
    float oy, ox, w;
    if (k9 < 4)       { oy = offy[k9];     ox = offx[k9];     w = a[k9]; }
    else if (k9 == 4) { oy = 0.f;          ox = 0.f;          w = aref;  }
    else              { oy = offy[k9 - 1]; ox = offx[k9 - 1]; w = a[k9 - 1]; }
    float ky = (float)(k9 / 3) - 1.f;
    float kx = (float)(k9 % 3) - 1.f;
    inter += w * bilin1(dimg, (float)y + ky + oy, (float)x + kx + ox);
  }
  inter = fmaxf(inter, 0.f);
  float cd = dimg[p];
  out[(size_t)b * HW_ + p] = fmaxf(0.7f * cd + 0.3f * inter, 0.f);
}

// ---------------------------------------------------------------------------
extern "C" void kernel_launch(void* const* d_in, const int* in_sizes, int n_in,
                              void* d_out, int out_size, void* d_ws, size_t ws_size,
                              hipStream_t stream)
{
  const float* disp   = (const float*)d_in[0];
  const float* normal = (const float*)d_in[1];
  const float* left   = (const float*)d_in[2];
  const float* right  = (const float*)d_in[3];
  const float* conf   = (const float*)d_in[4];
  const float* w1     = (const float*)d_in[5];
  const float* g1     = (const float*)d_in[6];
  const float* b1     = (const float*)d_in[7];
  const float* m1     = (const float*)d_in[8];
  const float* v1     = (const float*)d_in[9];
  const float* w2     = (const float*)d_in[10];
  const float* g2     = (const float*)d_in[11];
  const float* b2     = (const float*)d_in[12];
  const float* m2     = (const float*)d_in[13];
  const float* v2     = (const float*)d_in[14];
  const float* w3     = (const float*)d_in[15];
  const float* asc    = (const float*)d_in[16];
  float* out = (float*)d_out;

  // Band buffers: guid (12ch, bh+6), x1 (32ch, bh+4), x2 (64ch, bh+2).
  // oa (24ch, bh) aliases the ws start (guid+x1 dead by conv3).
  struct Cfg { int g, bh; };
  const Cfg cfgs[] = {{4, 384}, {2, 384}, {1, 384}, {4, 96}, {2, 96},
                      {1, 96}, {1, 48}, {1, 24}, {1, 12}, {1, 8}, {1, 4}};
  int G = 1, BH = 4;
  for (const Cfg& c : cfgs) {
    size_t rows = (size_t)12 * (c.bh + 6) + (size_t)32 * (c.bh + 4) +
                  (size_t)64 * (c.bh + 2);
    size_t need = (size_t)c.g * rows * W_ * sizeof(float);
    if (need <= ws_size) { G = c.g; BH = c.bh; break; }
  }

  float* ws = (float*)d_ws;
  float* guid_buf = ws;
  float* x1_buf   = guid_buf + (size_t)G * 12 * (BH + 6) * W_;
  float* x2_buf   = x1_buf   + (size_t)G * 32 * (BH + 4) * W_;
  float* oa_buf   = ws;  // alias: guid+x1 dead once conv3 runs

  const int tilesX = W_ / 32;  // 40

  for (int b0 = 0; b0 < B_; b0 += G) {
    for (int y0 = 0; y0 < H_; y0 += BH) {
      const int rows_out = min(BH, H_ - y0);
      const int y_x2_0 = max(y0 - 1, 0);
      const int y_x2_1 = min(y0 + rows_out + 1, H_);
      const int rows_x2 = y_x2_1 - y_x2_0;
      const int y_x1_0 = max(y0 - 2, 0);
      const int y_x1_1 = min(y0 + rows_out + 2, H_);
      const int rows_x1 = y_x1_1 - y_x1_0;
      const int y_g_0 = max(y0 - 3, 0);
      const int y_g_1 = min(y0 + rows_out + 3, H_);
      const int rows_g = y_g_1 - y_g_0;

      {
        int n = G * rows_g * W_;
        guidance_band<<<(n + 255) / 256, 256, 0, stream>>>(
            disp, normal, left, right, guid_buf, b0, G, y_g_0, rows_g);
      }
      {
        // 12 -> 32: NCO=4, CHUNK=4 (3 rounds)
        int grid = 4 * tilesX * ((rows_x1 + 31) / 32) * G;
        conv3x3_px4<12, 32, 4, true><<<grid, 256, 0, stream>>>(
            guid_buf, w1, g1, b1, m1, v1, x1_buf,
            y_g_0, rows_g, y_x1_0, rows_x1);
      }
      {
        // 32 -> 64: NCO=8, CHUNK=4 (8 rounds)
        int grid = 8 * tilesX * ((rows_x2 + 31) / 32) * G;
        conv3x3_px4<32, 64, 4, true><<<grid, 256, 0, stream>>>(
            x1_buf, w2, g2, b2, m2, v2, x2_buf,
            y_x1_0, rows_x1, y_x2_0, rows_x2);
      }
      {
        // 64 -> 24: NCO=3, CHUNK=4 (16 rounds)
        int grid = 3 * tilesX * ((rows_out + 31) / 32) * G;
        conv3x3_px4<64, 24, 4, false><<<grid, 256, 0, stream>>>(
            x2_buf, w3, nullptr, nullptr, nullptr, nullptr, oa_buf,
            y_x2_0, rows_x2, y0, rows_out);
      }
      {
        int n = G * rows_out * W_;
        final_band<<<(n + 255) / 256, 256, 0, stream>>>(
            oa_buf, conf, disp, asc, out, b0, G, y0, rows_out);
      }
    }
  }
}